// Round 5
// baseline (1225.739 us; speedup 1.0000x reference)
//
#include <hip/hip_runtime.h>
#include <math.h>

#define NN 150000      // nodes
#define NE 4800000     // edges (without self loops)
#define HD 16          // hidden dim
#define NBUCK 586      // ceil(NN/256) buckets of 256 nodes
#define BSH 8
#define NBLK 256       // partition chunks
#define CHUNK 18750    // NE / NBLK (exact)
#define NSCAN 150016   // NBUCK * NBLK
#define SCANB 147      // ceil(NSCAN / 1024)

// ---- bf16 helpers (bit-level, round-to-nearest-even) ----
__device__ __forceinline__ float bf2f(unsigned short u) {
    return __uint_as_float(((unsigned int)u) << 16);
}
__device__ __forceinline__ unsigned short f2bf(float f) {
    unsigned int x = __float_as_uint(f);
    return (unsigned short)((x + 0x7FFFu + ((x >> 16) & 1u)) >> 16);
}

// ================= phase A: partition edges into 586 dst-buckets =================

__global__ __launch_bounds__(512) void k_part_count(const int* __restrict__ dst,
                                                    int* __restrict__ C) {
    __shared__ int h[NBUCK];
    for (int i = threadIdx.x; i < NBUCK; i += 512) h[i] = 0;
    __syncthreads();
    int base = blockIdx.x * CHUNK;
    for (int i = threadIdx.x; i < CHUNK; i += 512)
        atomicAdd(&h[dst[base + i] >> BSH], 1);
    __syncthreads();
    for (int i = threadIdx.x; i < NBUCK; i += 512) C[i * NBLK + blockIdx.x] = h[i];
}

__global__ void k_scanA(int* __restrict__ C, int* __restrict__ psum) {
    __shared__ int s[1024];
    int t = threadIdx.x;
    int i = blockIdx.x * 1024 + t;
    int v = (i < NSCAN) ? C[i] : 0;
    s[t] = v;
    __syncthreads();
    for (int off = 1; off < 1024; off <<= 1) {
        int x = (t >= off) ? s[t - off] : 0;
        __syncthreads();
        s[t] += x;
        __syncthreads();
    }
    if (i < NSCAN) C[i] = s[t] - v;       // local exclusive
    if (t == 1023) psum[blockIdx.x] = s[1023];
}

__global__ void k_scanB(int* __restrict__ psum) {
    __shared__ int s[512];
    int t = threadIdx.x;
    int v = (t < SCANB) ? psum[t] : 0;
    s[t] = v;
    __syncthreads();
    for (int off = 1; off < 512; off <<= 1) {
        int x = (t >= off) ? s[t - off] : 0;
        __syncthreads();
        s[t] += x;
        __syncthreads();
    }
    if (t < SCANB) psum[t] = s[t] - v;    // exclusive
}

__global__ void k_scanC(int* __restrict__ C, const int* __restrict__ psum,
                        int* __restrict__ bstart) {
    int i = blockIdx.x * 1024 + threadIdx.x;
    if (i >= NSCAN) return;
    int v = C[i] + psum[blockIdx.x];
    C[i] = v;
    if ((i & (NBLK - 1)) == 0) bstart[i >> BSH] = v;   // (b, chunk=0) -> bucket base
    if (i == 0) bstart[NBUCK] = NE;
}

// scatter edges into bucket-grouped packed array. XCD-aware chunk swizzle:
// chunks adjacent in memory are processed by blocks on the SAME XCD, so
// run-boundary cache lines stay in one L2 (cuts cross-XCD write amplification).
__global__ __launch_bounds__(512) void k_part_scatter(const int* __restrict__ src,
                                                      const int* __restrict__ dst,
                                                      const int* __restrict__ C,
                                                      int* __restrict__ packed) {
    __shared__ int cur[NBUCK];
    int bid = blockIdx.x;
    int m = ((bid & 7) << 5) | (bid >> 3);   // bijective on [0,256): same-XCD blocks get adjacent chunks
    for (int i = threadIdx.x; i < NBUCK; i += 512) cur[i] = C[i * NBLK + m];
    __syncthreads();
    int base = m * CHUNK;
    for (int i = threadIdx.x; i < CHUNK; i += 512) {
        int s = src[base + i], d = dst[base + i];
        int pos = atomicAdd(&cur[d >> BSH], 1);
        packed[pos] = (s << BSH) | (d & 255);   // src < 2^18, local dst < 2^8
    }
}

// ============ fused degree hist + dinv + input transform (per bucket) ============
__global__ __launch_bounds__(512) void k_deg_transform(const int* __restrict__ packed,
                                                       const int* __restrict__ bstart,
                                                       const float* __restrict__ x,
                                                       const float* __restrict__ W,
                                                       float* __restrict__ dinv,
                                                       unsigned short* __restrict__ tA) {
    __shared__ int deg[256];
    __shared__ float sdinv[256];
    __shared__ float sx[256 * 3];
    __shared__ float sW[3 * HD];
    int b = blockIdx.x, t = threadIdx.x;
    int v0 = b << BSH;
    int nv = min(256, NN - v0);
    if (t < 256) deg[t] = 0;
    if (t < 3 * HD) sW[t] = W[t];
    __syncthreads();
    int e0 = bstart[b], e1 = bstart[b + 1];
    for (int e = e0 + t; e < e1; e += 512)
        atomicAdd(&deg[packed[e] & 255], 1);
    for (int i = t; i < nv * 3; i += 512) sx[i] = x[v0 * 3 + i];
    __syncthreads();
    if (t < 256) {
        float di = rsqrtf((float)(deg[t] + 1));   // +1: self loop
        sdinv[t] = di;
        if (t < nv) dinv[v0 + t] = di;
    }
    __syncthreads();
    for (int idx = t; idx < nv * HD; idx += 512) {
        int n = idx >> 4, j = idx & 15;
        float s = sx[n * 3 + 0] * sW[j] + sx[n * 3 + 1] * sW[HD + j] + sx[n * 3 + 2] * sW[2 * HD + j];
        tA[(size_t)(v0 + n) * HD + j] = f2bf(s * sdinv[n]);
    }
}

// ============ fused gather(LDS atomics) + relu + next transform (16 -> 16) ============
__global__ __launch_bounds__(512) void k_gather_mid(const int* __restrict__ packed,
                                                    const int* __restrict__ bstart,
                                                    const unsigned short* __restrict__ t,
                                                    const float* __restrict__ dinv,
                                                    const float* __restrict__ b,
                                                    const float* __restrict__ W,
                                                    unsigned short* __restrict__ tnext) {
    __shared__ float acc[256 * HD];   // 16 KB
    __shared__ float sW[HD * HD];
    __shared__ float sb[HD];
    int bk = blockIdx.x, tid = threadIdx.x;
    int v0 = bk << BSH;
    int nv = min(256, NN - v0);
    for (int i = tid; i < 256 * HD; i += 512) acc[i] = 0.0f;
    if (tid < HD * HD) sW[tid] = W[tid];
    if (tid < HD) sb[tid] = b[tid];
    __syncthreads();
    int e0 = bstart[bk], e1 = bstart[bk + 1];
    int g = tid >> 4, j = tid & 15;
    for (int e = e0 + g; e < e1; e += 32) {
        int p = packed[e];
        atomicAdd(&acc[(p & 255) * HD + j], bf2f(t[(size_t)(p >> BSH) * HD + j]));
    }
    __syncthreads();
    // phase 1: h = relu((acc + self)*dinv + b), overwrite acc with h
    for (int n = g; n < nv; n += 32) {
        int v = v0 + n;
        float sum = acc[n * HD + j] + bf2f(t[(size_t)v * HD + j]);
        acc[n * HD + j] = fmaxf(sum * dinv[v] + sb[j], 0.0f);
    }
    __syncthreads();
    // phase 2: tnext = (h @ W) * dinv
    for (int n = g; n < nv; n += 32) {
        int v = v0 + n;
        float o = 0.0f;
#pragma unroll
        for (int k = 0; k < HD; ++k) o += acc[n * HD + k] * sW[k * HD + j];
        tnext[(size_t)v * HD + j] = f2bf(o * dinv[v]);
    }
}

// ============ fused gather + relu + output dot (16 -> 1) ============
__global__ __launch_bounds__(512) void k_gather_out(const int* __restrict__ packed,
                                                    const int* __restrict__ bstart,
                                                    const unsigned short* __restrict__ t,
                                                    const float* __restrict__ dinv,
                                                    const float* __restrict__ b,
                                                    const float* __restrict__ Wout,
                                                    float* __restrict__ t3) {
    __shared__ float acc[256 * HD];
    __shared__ float sW[HD];
    __shared__ float sb[HD];
    int bk = blockIdx.x, tid = threadIdx.x;
    int v0 = bk << BSH;
    int nv = min(256, NN - v0);
    for (int i = tid; i < 256 * HD; i += 512) acc[i] = 0.0f;
    if (tid < HD) { sW[tid] = Wout[tid]; sb[tid] = b[tid]; }
    __syncthreads();
    int e0 = bstart[bk], e1 = bstart[bk + 1];
    int g = tid >> 4, j = tid & 15;
    for (int e = e0 + g; e < e1; e += 32) {
        int p = packed[e];
        atomicAdd(&acc[(p & 255) * HD + j], bf2f(t[(size_t)(p >> BSH) * HD + j]));
    }
    __syncthreads();
    for (int n = g; n < nv; n += 32) {
        int v = v0 + n;
        float di = dinv[v];
        float sum = acc[n * HD + j] + bf2f(t[(size_t)v * HD + j]);
        float h = fmaxf(sum * di + sb[j], 0.0f);
        float d = h * sW[j];
        d += __shfl_xor(d, 1);
        d += __shfl_xor(d, 2);
        d += __shfl_xor(d, 4);
        d += __shfl_xor(d, 8);
        if (j == 0) t3[v] = d * di;
    }
}

// ============ final: gather t3 (scalar), bias, sigmoid ============
__global__ __launch_bounds__(512) void k_gather_final(const int* __restrict__ packed,
                                                      const int* __restrict__ bstart,
                                                      const float* __restrict__ t3,
                                                      const float* __restrict__ dinv,
                                                      const float* __restrict__ b_out,
                                                      float* __restrict__ out) {
    __shared__ float facc[256];
    int bk = blockIdx.x, tid = threadIdx.x;
    int v0 = bk << BSH;
    int nv = min(256, NN - v0);
    if (tid < 256) facc[tid] = 0.0f;
    __syncthreads();
    int e0 = bstart[bk], e1 = bstart[bk + 1];
    for (int e = e0 + tid; e < e1; e += 512) {
        int p = packed[e];
        atomicAdd(&facc[p & 255], t3[p >> BSH]);
    }
    __syncthreads();
    if (tid < nv) {
        int v = v0 + tid;
        float z = (facc[tid] + t3[v]) * dinv[v] + b_out[0];
        out[v] = 1.0f / (1.0f + expf(-z));
    }
}

extern "C" void kernel_launch(void* const* d_in, const int* in_sizes, int n_in,
                              void* d_out, int out_size, void* d_ws, size_t ws_size,
                              hipStream_t stream) {
    const float* x     = (const float*)d_in[0];
    const int*   ei    = (const int*)d_in[1];
    const float* W_in  = (const float*)d_in[2];
    const float* b_in  = (const float*)d_in[3];
    const float* W_mid = (const float*)d_in[4];
    const float* b_mid = (const float*)d_in[5];
    const float* W_out = (const float*)d_in[6];
    const float* b_out = (const float*)d_in[7];
    float* out = (float*)d_out;

    const int* src = ei;
    const int* dst = ei + NE;

    // workspace (~30.6 MB)
    char* p = (char*)d_ws;
    int*   C      = (int*)p;     p += sizeof(int) * NSCAN;
    int*   psum   = (int*)p;     p += sizeof(int) * 160;
    int*   bstart = (int*)p;     p += sizeof(int) * (NBUCK + 2);
    float* dinv   = (float*)p;   p += sizeof(float) * NN;
    int*   packed = (int*)p;     p += sizeof(int) * (size_t)NE;     // 19.2 MB, live all passes
    unsigned short* tA = (unsigned short*)p; p += sizeof(unsigned short) * (size_t)NN * HD;
    unsigned short* tB = (unsigned short*)p; p += sizeof(unsigned short) * (size_t)NN * HD;
    float* t3     = (float*)p;   p += sizeof(float) * NN;

    // ---- build bucket-grouped edge array ----
    k_part_count<<<NBLK, 512, 0, stream>>>(dst, C);
    k_scanA<<<SCANB, 1024, 0, stream>>>(C, psum);
    k_scanB<<<1, 512, 0, stream>>>(psum);
    k_scanC<<<SCANB, 1024, 0, stream>>>(C, psum, bstart);
    k_part_scatter<<<NBLK, 512, 0, stream>>>(src, dst, C, packed);

    // ---- degree + dinv + input transform ----
    k_deg_transform<<<NBUCK, 512, 0, stream>>>(packed, bstart, x, W_in, dinv, tA);

    // ---- layers ----
    k_gather_mid<<<NBUCK, 512, 0, stream>>>(packed, bstart, tA, dinv, b_in, W_mid, tB);
    k_gather_out<<<NBUCK, 512, 0, stream>>>(packed, bstart, tB, dinv, b_mid, W_out, t3);
    k_gather_final<<<NBUCK, 512, 0, stream>>>(packed, bstart, t3, dinv, b_out, out);
}

// Round 9
// 366.937 us; speedup vs baseline: 3.3405x; 3.3405x over previous
//
#include <hip/hip_runtime.h>
#include <math.h>

#define NN 150000      // nodes (== 16 * 9375)
#define NE 4800000     // edges (without self loops)
#define HD 16          // hidden dim
#define NBUCK 586      // ceil(NN/256) buckets of 256 nodes
#define BSH 8
#define NBLK 256       // partition chunks
#define CHUNK 18750    // NE / NBLK (exact)
#define NSCAN 150016   // NBUCK * NBLK
#define SCANB 147      // ceil(NSCAN / 1024)

// ---- bf16 helpers (bit-level, round-to-nearest-even) ----
__device__ __forceinline__ float bf2f(unsigned short u) {
    return __uint_as_float(((unsigned int)u) << 16);
}
__device__ __forceinline__ unsigned short f2bf(float f) {
    unsigned int x = __float_as_uint(f);
    return (unsigned short)((x + 0x7FFFu + ((x >> 16) & 1u)) >> 16);
}

// ================= phase A: partition edges into 586 dst-buckets =================

__global__ __launch_bounds__(512) void k_part_count(const int* __restrict__ dst,
                                                    int* __restrict__ C) {
    __shared__ int h[NBUCK];
    for (int i = threadIdx.x; i < NBUCK; i += 512) h[i] = 0;
    __syncthreads();
    int base = blockIdx.x * CHUNK;
    for (int i = threadIdx.x; i < CHUNK; i += 512)
        atomicAdd(&h[dst[base + i] >> BSH], 1);
    __syncthreads();
    for (int i = threadIdx.x; i < NBUCK; i += 512) C[i * NBLK + blockIdx.x] = h[i];
}

__global__ void k_scanA(int* __restrict__ C, int* __restrict__ psum) {
    __shared__ int s[1024];
    int t = threadIdx.x;
    int i = blockIdx.x * 1024 + t;
    int v = (i < NSCAN) ? C[i] : 0;
    s[t] = v;
    __syncthreads();
    for (int off = 1; off < 1024; off <<= 1) {
        int x = (t >= off) ? s[t - off] : 0;
        __syncthreads();
        s[t] += x;
        __syncthreads();
    }
    if (i < NSCAN) C[i] = s[t] - v;       // local exclusive
    if (t == 1023) psum[blockIdx.x] = s[1023];
}

__global__ void k_scanB(int* __restrict__ psum) {
    __shared__ int s[512];
    int t = threadIdx.x;
    int v = (t < SCANB) ? psum[t] : 0;
    s[t] = v;
    __syncthreads();
    for (int off = 1; off < 512; off <<= 1) {
        int x = (t >= off) ? s[t - off] : 0;
        __syncthreads();
        s[t] += x;
        __syncthreads();
    }
    if (t < SCANB) psum[t] = s[t] - v;    // exclusive
}

__global__ void k_scanC(int* __restrict__ C, const int* __restrict__ psum,
                        int* __restrict__ bstart) {
    int i = blockIdx.x * 1024 + threadIdx.x;
    if (i >= NSCAN) return;
    int v = C[i] + psum[blockIdx.x];
    C[i] = v;
    if ((i & (NBLK - 1)) == 0) bstart[i >> BSH] = v;   // (b, chunk=0) -> bucket base
    if (i == 0) bstart[NBUCK] = NE;
}

// scatter edges into bucket-grouped packed array. Runs are ~32 edges (128 B);
// XCD-aware chunk swizzle: same-XCD blocks process adjacent chunks so run-boundary
// lines stay in one L2 (cuts cross-XCD write amplification).
__global__ __launch_bounds__(512) void k_part_scatter(const int* __restrict__ src,
                                                      const int* __restrict__ dst,
                                                      const int* __restrict__ C,
                                                      int* __restrict__ packed) {
    __shared__ int cur[NBUCK];
    int bid = blockIdx.x;
    int m = ((bid & 7) << 5) | (bid >> 3);   // bijective on [0,256)
    for (int i = threadIdx.x; i < NBUCK; i += 512) cur[i] = C[i * NBLK + m];
    __syncthreads();
    int base = m * CHUNK;
    for (int i = threadIdx.x; i < CHUNK; i += 512) {
        int s = src[base + i], d = dst[base + i];
        int pos = atomicAdd(&cur[d >> BSH], 1);
        packed[pos] = (s << BSH) | (d & 255);   // src < 2^18, local dst < 2^8
    }
}

// ================= phase B: per-bucket local counting sort =================
__global__ __launch_bounds__(256) void k_bucket_sort(const int* __restrict__ packed,
                                                     const int* __restrict__ bstart,
                                                     int* __restrict__ row_start,
                                                     float* __restrict__ dinv,
                                                     int* __restrict__ ssrc) {
    __shared__ int hist[256];
    __shared__ int fill[256];
    int b = blockIdx.x;
    int t = threadIdx.x;
    int v0 = b << BSH;
    int nv = min(256, NN - v0);
    int e0 = bstart[b], e1 = bstart[b + 1];
    hist[t] = 0;
    __syncthreads();
    for (int e = e0 + t; e < e1; e += 256)
        atomicAdd(&hist[packed[e] & 255], 1);
    __syncthreads();
    int cv = hist[t];
    __syncthreads();
    for (int off = 1; off < 256; off <<= 1) {
        int x = (t >= off) ? hist[t - off] : 0;
        __syncthreads();
        hist[t] += x;
        __syncthreads();
    }
    int excl = hist[t] - cv;
    if (t < nv) {
        row_start[v0 + t] = e0 + excl;
        fill[t] = e0 + excl;
        dinv[v0 + t] = rsqrtf((float)cv + 1.0f);   // +1: self loop
    }
    __syncthreads();
    for (int e = e0 + t; e < e1; e += 256) {
        int p = packed[e];
        int pos = atomicAdd(&fill[p & 255], 1);
        ssrc[pos] = p >> BSH;
    }
    if (b == 0 && t == 0) row_start[NN] = NE;
}

// ================= layer 1 transform: t = (x @ W_in) * dinv (bf16 out) =================
__global__ __launch_bounds__(256) void k_transform_in(const float* __restrict__ x,
                                                      const float* __restrict__ W,
                                                      const float* __restrict__ dinv,
                                                      unsigned short* __restrict__ t) {
    int gid = blockIdx.x * blockDim.x + threadIdx.x;
    if (gid >= NN * HD) return;
    int v = gid >> 4, j = gid & 15;
    float s = x[v * 3 + 0] * W[j] + x[v * 3 + 1] * W[HD + j] + x[v * 3 + 2] * W[2 * HD + j];
    t[gid] = f2bf(s * dinv[v]);
}

// ============ fused gather + relu + next transform (16 -> 16) ============
// 32 lanes per node: two 16-lane halves take alternating edges, each 4-way
// unrolled -> ~8 outstanding gathers per node; combine via shfl_xor(16).
__global__ __launch_bounds__(512) void k_gather_mid(const int* __restrict__ row_start,
                                                    const int* __restrict__ ssrc,
                                                    const unsigned short* __restrict__ t,
                                                    const float* __restrict__ dinv,
                                                    const float* __restrict__ b,
                                                    const float* __restrict__ W,
                                                    unsigned short* __restrict__ tnext) {
    __shared__ float sW[HD * HD];
    __shared__ float sh[16 * HD];
    int tid = threadIdx.x;
    if (tid < HD * HD) sW[tid] = W[tid];
    int node = tid >> 5;            // 0..15
    int lane = tid & 31;
    int j = lane & 15;
    int half = lane >> 4;
    int v = blockIdx.x * 16 + node;
    int e0 = row_start[v], e1 = row_start[v + 1];
    float sum = 0.0f;
    int e = e0 + half;
    for (; e + 6 < e1; e += 8) {
        int s0 = ssrc[e], s1 = ssrc[e + 2], s2 = ssrc[e + 4], s3 = ssrc[e + 6];
        sum += bf2f(t[(size_t)s0 * HD + j]) + bf2f(t[(size_t)s1 * HD + j])
             + bf2f(t[(size_t)s2 * HD + j]) + bf2f(t[(size_t)s3 * HD + j]);
    }
    for (; e < e1; e += 2) sum += bf2f(t[(size_t)ssrc[e] * HD + j]);
    if (half == 0) sum += bf2f(t[(size_t)v * HD + j]);   // self loop
    sum += __shfl_xor(sum, 16);
    if (half == 0) {
        float h = fmaxf(sum * dinv[v] + b[j], 0.0f);
        sh[node * HD + j] = h;
    }
    __syncthreads();
    if (tid < 256) {
        int n = tid >> 4, jj = tid & 15;
        int vv = blockIdx.x * 16 + n;
        float o = 0.0f;
#pragma unroll
        for (int k = 0; k < HD; ++k) o += sh[n * HD + k] * sW[k * HD + jj];
        tnext[(size_t)vv * HD + jj] = f2bf(o * dinv[vv]);
    }
}

// ============ fused gather + relu + output dot (16 -> 1) ============
__global__ __launch_bounds__(512) void k_gather_out(const int* __restrict__ row_start,
                                                    const int* __restrict__ ssrc,
                                                    const unsigned short* __restrict__ t,
                                                    const float* __restrict__ dinv,
                                                    const float* __restrict__ b,
                                                    const float* __restrict__ Wout,
                                                    float* __restrict__ t3) {
    int tid = threadIdx.x;
    int node = tid >> 5;
    int lane = tid & 31;
    int j = lane & 15;
    int half = lane >> 4;
    int v = blockIdx.x * 16 + node;
    int e0 = row_start[v], e1 = row_start[v + 1];
    float sum = 0.0f;
    int e = e0 + half;
    for (; e + 6 < e1; e += 8) {
        int s0 = ssrc[e], s1 = ssrc[e + 2], s2 = ssrc[e + 4], s3 = ssrc[e + 6];
        sum += bf2f(t[(size_t)s0 * HD + j]) + bf2f(t[(size_t)s1 * HD + j])
             + bf2f(t[(size_t)s2 * HD + j]) + bf2f(t[(size_t)s3 * HD + j]);
    }
    for (; e < e1; e += 2) sum += bf2f(t[(size_t)ssrc[e] * HD + j]);
    if (half == 0) sum += bf2f(t[(size_t)v * HD + j]);   // self loop
    sum += __shfl_xor(sum, 16);
    float di = dinv[v];
    float h = fmaxf(sum * di + b[j], 0.0f);
    float d = h * Wout[j];
    d += __shfl_xor(d, 1);
    d += __shfl_xor(d, 2);
    d += __shfl_xor(d, 4);
    d += __shfl_xor(d, 8);
    if (lane == 0) t3[v] = d * di;
}

// ============ final: gather t3 (scalar), bias, sigmoid ============
__global__ __launch_bounds__(256) void k_gather_final(const int* __restrict__ row_start,
                                                      const int* __restrict__ ssrc,
                                                      const float* __restrict__ t3,
                                                      const float* __restrict__ dinv,
                                                      const float* __restrict__ b_out,
                                                      float* __restrict__ out) {
    int tid = threadIdx.x;
    int v = blockIdx.x * 16 + (tid >> 4);
    int l = tid & 15;
    int e0 = row_start[v], e1 = row_start[v + 1];
    float sum = 0.0f;
    for (int e = e0 + l; e < e1; e += 16) sum += t3[ssrc[e]];
    sum += __shfl_xor(sum, 1);
    sum += __shfl_xor(sum, 2);
    sum += __shfl_xor(sum, 4);
    sum += __shfl_xor(sum, 8);
    if (l == 0) {
        float z = (sum + t3[v]) * dinv[v] + b_out[0];
        out[v] = 1.0f / (1.0f + expf(-z));
    }
}

extern "C" void kernel_launch(void* const* d_in, const int* in_sizes, int n_in,
                              void* d_out, int out_size, void* d_ws, size_t ws_size,
                              hipStream_t stream) {
    const float* x     = (const float*)d_in[0];
    const int*   ei    = (const int*)d_in[1];
    const float* W_in  = (const float*)d_in[2];
    const float* b_in  = (const float*)d_in[3];
    const float* W_mid = (const float*)d_in[4];
    const float* b_mid = (const float*)d_in[5];
    const float* W_out = (const float*)d_in[6];
    const float* b_out = (const float*)d_in[7];
    float* out = (float*)d_out;

    const int* src = ei;
    const int* dst = ei + NE;

    // workspace (~41 MB): tA/tB/t3 alias `packed` (dead after k_bucket_sort)
    char* p = (char*)d_ws;
    int*   C         = (int*)p;      p += sizeof(int) * NSCAN;
    int*   psum      = (int*)p;      p += sizeof(int) * 160;
    int*   bstart    = (int*)p;      p += sizeof(int) * (NBUCK + 2);
    int*   row_start = (int*)p;      p += sizeof(int) * (NN + 1);
    float* dinv      = (float*)p;    p += sizeof(float) * NN;
    int*   ssrc      = (int*)p;      p += sizeof(int) * (size_t)NE;   // live through gathers
    int*   packed    = (int*)p;      p += sizeof(int) * (size_t)NE;   // dead after bucket_sort
    unsigned short* tA = (unsigned short*)packed;                      // alias
    unsigned short* tB = tA + (size_t)NN * HD;                         // alias
    float* t3          = (float*)(tB + (size_t)NN * HD);               // alias

    const int gNH = (NN * HD + 255) / 256;  // 9375
    const int gV  = NN / 16;                // 9375

    // ---- build dst-bucketed CSR via two-level counting sort ----
    k_part_count<<<NBLK, 512, 0, stream>>>(dst, C);
    k_scanA<<<SCANB, 1024, 0, stream>>>(C, psum);
    k_scanB<<<1, 512, 0, stream>>>(psum);
    k_scanC<<<SCANB, 1024, 0, stream>>>(C, psum, bstart);
    k_part_scatter<<<NBLK, 512, 0, stream>>>(src, dst, C, packed);
    k_bucket_sort<<<NBUCK, 256, 0, stream>>>(packed, bstart, row_start, dinv, ssrc);

    // ---- layers ----
    k_transform_in<<<gNH, 256, 0, stream>>>(x, W_in, dinv, tA);
    k_gather_mid<<<gV, 512, 0, stream>>>(row_start, ssrc, tA, dinv, b_in, W_mid, tB);
    k_gather_out<<<gV, 512, 0, stream>>>(row_start, ssrc, tB, dinv, b_mid, W_out, t3);
    k_gather_final<<<gV, 256, 0, stream>>>(row_start, ssrc, t3, dinv, b_out, out);
}

// Round 11
// 331.755 us; speedup vs baseline: 3.6947x; 1.1060x over previous
//
#include <hip/hip_runtime.h>
#include <math.h>

#define NN 150000      // nodes (== 16 * 9375)
#define NE 4800000     // edges (without self loops)
#define HD 16          // hidden dim
#define NBUCK 586      // ceil(NN/256) buckets of 256 nodes
#define BSH 8
#define NBLK 256       // partition chunks
#define CHUNK 18750    // NE / NBLK (exact)
#define NSCAN 150016   // NBUCK * NBLK
#define SCANB 147      // ceil(NSCAN / 1024)

// ---- bf16 helpers (bit-level, round-to-nearest-even) ----
__device__ __forceinline__ float bf2f(unsigned short u) {
    return __uint_as_float(((unsigned int)u) << 16);
}
__device__ __forceinline__ unsigned short f2bf(float f) {
    unsigned int x = __float_as_uint(f);
    return (unsigned short)((x + 0x7FFFu + ((x >> 16) & 1u)) >> 16);
}

// ================= phase A: partition edges into 586 dst-buckets =================

__global__ __launch_bounds__(512) void k_part_count(const int* __restrict__ dst,
                                                    int* __restrict__ C) {
    __shared__ int h[NBUCK];
    for (int i = threadIdx.x; i < NBUCK; i += 512) h[i] = 0;
    __syncthreads();
    int base = blockIdx.x * CHUNK;
    for (int i = threadIdx.x; i < CHUNK; i += 512)
        atomicAdd(&h[dst[base + i] >> BSH], 1);
    __syncthreads();
    for (int i = threadIdx.x; i < NBUCK; i += 512) C[i * NBLK + blockIdx.x] = h[i];
}

__global__ void k_scanA(int* __restrict__ C, int* __restrict__ psum) {
    __shared__ int s[1024];
    int t = threadIdx.x;
    int i = blockIdx.x * 1024 + t;
    int v = (i < NSCAN) ? C[i] : 0;
    s[t] = v;
    __syncthreads();
    for (int off = 1; off < 1024; off <<= 1) {
        int x = (t >= off) ? s[t - off] : 0;
        __syncthreads();
        s[t] += x;
        __syncthreads();
    }
    if (i < NSCAN) C[i] = s[t] - v;       // local exclusive
    if (t == 1023) psum[blockIdx.x] = s[1023];
}

__global__ void k_scanB(int* __restrict__ psum) {
    __shared__ int s[512];
    int t = threadIdx.x;
    int v = (t < SCANB) ? psum[t] : 0;
    s[t] = v;
    __syncthreads();
    for (int off = 1; off < 512; off <<= 1) {
        int x = (t >= off) ? s[t - off] : 0;
        __syncthreads();
        s[t] += x;
        __syncthreads();
    }
    if (t < SCANB) psum[t] = s[t] - v;    // exclusive
}

__global__ void k_scanC(int* __restrict__ C, const int* __restrict__ psum,
                        int* __restrict__ bstart) {
    int i = blockIdx.x * 1024 + threadIdx.x;
    if (i >= NSCAN) return;
    int v = C[i] + psum[blockIdx.x];
    C[i] = v;
    if ((i & (NBLK - 1)) == 0) bstart[i >> BSH] = v;   // (b, chunk=0) -> bucket base
    if (i == 0) bstart[NBUCK] = NE;
}

// scatter edges into bucket-grouped packed array. Runs are ~32 edges (128 B);
// XCD-aware chunk swizzle keeps run-boundary lines in one L2.
__global__ __launch_bounds__(512) void k_part_scatter(const int* __restrict__ src,
                                                      const int* __restrict__ dst,
                                                      const int* __restrict__ C,
                                                      int* __restrict__ packed) {
    __shared__ int cur[NBUCK];
    int bid = blockIdx.x;
    int m = ((bid & 7) << 5) | (bid >> 3);   // bijective on [0,256)
    for (int i = threadIdx.x; i < NBUCK; i += 512) cur[i] = C[i * NBLK + m];
    __syncthreads();
    int base = m * CHUNK;
    for (int i = threadIdx.x; i < CHUNK; i += 512) {
        int s = src[base + i], d = dst[base + i];
        int pos = atomicAdd(&cur[d >> BSH], 1);
        packed[pos] = (s << BSH) | (d & 255);   // src < 2^18, local dst < 2^8
    }
}

// ================= phase B: per-bucket local counting sort =================
__global__ __launch_bounds__(256) void k_bucket_sort(const int* __restrict__ packed,
                                                     const int* __restrict__ bstart,
                                                     int* __restrict__ row_start,
                                                     float* __restrict__ dinv,
                                                     int* __restrict__ ssrc) {
    __shared__ int hist[256];
    __shared__ int fill[256];
    int b = blockIdx.x;
    int t = threadIdx.x;
    int v0 = b << BSH;
    int nv = min(256, NN - v0);
    int e0 = bstart[b], e1 = bstart[b + 1];
    hist[t] = 0;
    __syncthreads();
    for (int e = e0 + t; e < e1; e += 256)
        atomicAdd(&hist[packed[e] & 255], 1);
    __syncthreads();
    int cv = hist[t];
    __syncthreads();
    for (int off = 1; off < 256; off <<= 1) {
        int x = (t >= off) ? hist[t - off] : 0;
        __syncthreads();
        hist[t] += x;
        __syncthreads();
    }
    int excl = hist[t] - cv;
    if (t < nv) {
        row_start[v0 + t] = e0 + excl;
        fill[t] = e0 + excl;
        dinv[v0 + t] = rsqrtf((float)cv + 1.0f);   // +1: self loop
    }
    __syncthreads();
    for (int e = e0 + t; e < e1; e += 256) {
        int p = packed[e];
        int pos = atomicAdd(&fill[p & 255], 1);
        ssrc[pos] = p >> BSH;
    }
    if (b == 0 && t == 0) row_start[NN] = NE;
}

// ================= layer 1 transform: t = (x @ W_in) * dinv (bf16 out) =================
__global__ __launch_bounds__(256) void k_transform_in(const float* __restrict__ x,
                                                      const float* __restrict__ W,
                                                      const float* __restrict__ dinv,
                                                      unsigned short* __restrict__ t) {
    int gid = blockIdx.x * blockDim.x + threadIdx.x;
    if (gid >= NN * HD) return;
    int v = gid >> 4, j = gid & 15;
    float s = x[v * 3 + 0] * W[j] + x[v * 3 + 1] * W[HD + j] + x[v * 3 + 2] * W[2 * HD + j];
    t[gid] = f2bf(s * dinv[v]);
}

// ============ fused gather + relu + next transform (16 -> 16) ============
// 32 lanes per node, 8 lanes per edge (2 features/lane as one u32 load):
// one gather instruction services 4 edges; unroll x2 -> 8 edges in flight.
// Feature-pair partial sums recombined via shfl_xor(8), shfl_xor(16).
__global__ __launch_bounds__(512) void k_gather_mid(const int* __restrict__ row_start,
                                                    const int* __restrict__ ssrc,
                                                    const unsigned short* __restrict__ t,
                                                    const float* __restrict__ dinv,
                                                    const float* __restrict__ b,
                                                    const float* __restrict__ W,
                                                    unsigned short* __restrict__ tnext) {
    __shared__ float sW[HD * HD];
    __shared__ float sh[16 * HD];
    int tid = threadIdx.x;
    if (tid < HD * HD) sW[tid] = W[tid];
    int node = tid >> 5;            // 0..15
    int lane = tid & 31;
    int sub  = lane >> 3;           // 0..3: edge slot
    int fl   = lane & 7;            // feature pair: j = 2*fl, 2*fl+1
    int v = blockIdx.x * 16 + node;
    int e0 = row_start[v], e1 = row_start[v + 1];
    float sx = 0.0f, sy = 0.0f;
    int e = e0 + sub;
    for (; e + 4 < e1; e += 8) {    // slots e and e+4 both valid for this sub
        int sA = ssrc[e], sB = ssrc[e + 4];
        unsigned int wA = *(const unsigned int*)(t + (size_t)sA * HD + 2 * fl);
        unsigned int wB = *(const unsigned int*)(t + (size_t)sB * HD + 2 * fl);
        sx += bf2f((unsigned short)wA) + bf2f((unsigned short)wB);
        sy += bf2f((unsigned short)(wA >> 16)) + bf2f((unsigned short)(wB >> 16));
    }
    for (; e < e1; e += 4) {
        unsigned int w = *(const unsigned int*)(t + (size_t)ssrc[e] * HD + 2 * fl);
        sx += bf2f((unsigned short)w);
        sy += bf2f((unsigned short)(w >> 16));
    }
    if (sub == 0) {                 // self loop, counted once
        unsigned int w = *(const unsigned int*)(t + (size_t)v * HD + 2 * fl);
        sx += bf2f((unsigned short)w);
        sy += bf2f((unsigned short)(w >> 16));
    }
    sx += __shfl_xor(sx, 8);  sx += __shfl_xor(sx, 16);
    sy += __shfl_xor(sy, 8);  sy += __shfl_xor(sy, 16);
    if (sub == 0) {
        float di = dinv[v];
        sh[node * HD + 2 * fl]     = fmaxf(sx * di + b[2 * fl], 0.0f);
        sh[node * HD + 2 * fl + 1] = fmaxf(sy * di + b[2 * fl + 1], 0.0f);
    }
    __syncthreads();
    if (tid < 256) {
        int n = tid >> 4, jj = tid & 15;
        int vv = blockIdx.x * 16 + n;
        float o = 0.0f;
#pragma unroll
        for (int k = 0; k < HD; ++k) o += sh[n * HD + k] * sW[k * HD + jj];
        tnext[(size_t)vv * HD + jj] = f2bf(o * dinv[vv]);
    }
}

// ============ fused gather + relu + output dot (16 -> 1) ============
__global__ __launch_bounds__(512) void k_gather_out(const int* __restrict__ row_start,
                                                    const int* __restrict__ ssrc,
                                                    const unsigned short* __restrict__ t,
                                                    const float* __restrict__ dinv,
                                                    const float* __restrict__ b,
                                                    const float* __restrict__ Wout,
                                                    float* __restrict__ t3) {
    int tid = threadIdx.x;
    int node = tid >> 5;
    int lane = tid & 31;
    int sub  = lane >> 3;
    int fl   = lane & 7;
    int v = blockIdx.x * 16 + node;
    int e0 = row_start[v], e1 = row_start[v + 1];
    float sx = 0.0f, sy = 0.0f;
    int e = e0 + sub;
    for (; e + 4 < e1; e += 8) {
        int sA = ssrc[e], sB = ssrc[e + 4];
        unsigned int wA = *(const unsigned int*)(t + (size_t)sA * HD + 2 * fl);
        unsigned int wB = *(const unsigned int*)(t + (size_t)sB * HD + 2 * fl);
        sx += bf2f((unsigned short)wA) + bf2f((unsigned short)wB);
        sy += bf2f((unsigned short)(wA >> 16)) + bf2f((unsigned short)(wB >> 16));
    }
    for (; e < e1; e += 4) {
        unsigned int w = *(const unsigned int*)(t + (size_t)ssrc[e] * HD + 2 * fl);
        sx += bf2f((unsigned short)w);
        sy += bf2f((unsigned short)(w >> 16));
    }
    if (sub == 0) {
        unsigned int w = *(const unsigned int*)(t + (size_t)v * HD + 2 * fl);
        sx += bf2f((unsigned short)w);
        sy += bf2f((unsigned short)(w >> 16));
    }
    sx += __shfl_xor(sx, 8);  sx += __shfl_xor(sx, 16);
    sy += __shfl_xor(sy, 8);  sy += __shfl_xor(sy, 16);
    float di = dinv[v];
    float hx = fmaxf(sx * di + b[2 * fl], 0.0f);
    float hy = fmaxf(sy * di + b[2 * fl + 1], 0.0f);
    float d = hx * Wout[2 * fl] + hy * Wout[2 * fl + 1];
    d += __shfl_xor(d, 1);
    d += __shfl_xor(d, 2);
    d += __shfl_xor(d, 4);
    if (lane == 0) t3[v] = d * di;
}

// ============ final: gather t3 (scalar), bias, sigmoid ============
__global__ __launch_bounds__(256) void k_gather_final(const int* __restrict__ row_start,
                                                      const int* __restrict__ ssrc,
                                                      const float* __restrict__ t3,
                                                      const float* __restrict__ dinv,
                                                      const float* __restrict__ b_out,
                                                      float* __restrict__ out) {
    int tid = threadIdx.x;
    int v = blockIdx.x * 16 + (tid >> 4);
    int l = tid & 15;
    int e0 = row_start[v], e1 = row_start[v + 1];
    float sum = 0.0f;
    for (int e = e0 + l; e < e1; e += 16) sum += t3[ssrc[e]];
    sum += __shfl_xor(sum, 1);
    sum += __shfl_xor(sum, 2);
    sum += __shfl_xor(sum, 4);
    sum += __shfl_xor(sum, 8);
    if (l == 0) {
        float z = (sum + t3[v]) * dinv[v] + b_out[0];
        out[v] = 1.0f / (1.0f + expf(-z));
    }
}

extern "C" void kernel_launch(void* const* d_in, const int* in_sizes, int n_in,
                              void* d_out, int out_size, void* d_ws, size_t ws_size,
                              hipStream_t stream) {
    const float* x     = (const float*)d_in[0];
    const int*   ei    = (const int*)d_in[1];
    const float* W_in  = (const float*)d_in[2];
    const float* b_in  = (const float*)d_in[3];
    const float* W_mid = (const float*)d_in[4];
    const float* b_mid = (const float*)d_in[5];
    const float* W_out = (const float*)d_in[6];
    const float* b_out = (const float*)d_in[7];
    float* out = (float*)d_out;

    const int* src = ei;
    const int* dst = ei + NE;

    // workspace (~41 MB): tA/tB/t3 alias `packed` (dead after k_bucket_sort)
    char* p = (char*)d_ws;
    int*   C         = (int*)p;      p += sizeof(int) * NSCAN;
    int*   psum      = (int*)p;      p += sizeof(int) * 160;
    int*   bstart    = (int*)p;      p += sizeof(int) * (NBUCK + 2);
    int*   row_start = (int*)p;      p += sizeof(int) * (NN + 1);
    float* dinv      = (float*)p;    p += sizeof(float) * NN;
    int*   ssrc      = (int*)p;      p += sizeof(int) * (size_t)NE;   // live through gathers
    int*   packed    = (int*)p;      p += sizeof(int) * (size_t)NE;   // dead after bucket_sort
    unsigned short* tA = (unsigned short*)packed;                      // alias
    unsigned short* tB = tA + (size_t)NN * HD;                         // alias
    float* t3          = (float*)(tB + (size_t)NN * HD);               // alias

    const int gNH = (NN * HD + 255) / 256;  // 9375
    const int gV  = NN / 16;                // 9375

    // ---- build dst-bucketed CSR via two-level counting sort ----
    k_part_count<<<NBLK, 512, 0, stream>>>(dst, C);
    k_scanA<<<SCANB, 1024, 0, stream>>>(C, psum);
    k_scanB<<<1, 512, 0, stream>>>(psum);
    k_scanC<<<SCANB, 1024, 0, stream>>>(C, psum, bstart);
    k_part_scatter<<<NBLK, 512, 0, stream>>>(src, dst, C, packed);
    k_bucket_sort<<<NBUCK, 256, 0, stream>>>(packed, bstart, row_start, dinv, ssrc);

    // ---- layers ----
    k_transform_in<<<gNH, 256, 0, stream>>>(x, W_in, dinv, tA);
    k_gather_mid<<<gV, 512, 0, stream>>>(row_start, ssrc, tA, dinv, b_in, W_mid, tB);
    k_gather_out<<<gV, 512, 0, stream>>>(row_start, ssrc, tB, dinv, b_mid, W_out, t3);
    k_gather_final<<<gV, 256, 0, stream>>>(row_start, ssrc, t3, dinv, b_out, out);
}